// Round 6
// baseline (168.154 us; speedup 1.0000x reference)
//
#include <hip/hip_runtime.h>
#include <hip/hip_bf16.h>
#include <math.h>

// SpikingNeuralNetwork: 3 chained bf16-MFMA GEMMs + fused elementwise epilogues.
// N = 2048. Round 6: round-2 geometry (128x128, 8 waves, BK=64, 2-phase dbuf)
// with the K-loop unrolled x2 so LDS buffer indices are COMPILE-TIME constants.
// Runtime `cur` indices defeat LLVM alias analysis: gload_lds writes to
// As[cur^1] vs ds_reads from As[cur] force a conservative vmcnt(0) before the
// reads, serializing stage+compute. Literal buffers -> provably disjoint ->
// the only drain is at __syncthreads(), a full compute-phase after load issue.

#define NN 2048
#define BK 64
#define KT (NN / BK)    // 32 K-tiles
#define NT (NN / 128)   // 16 tiles per dim

typedef __attribute__((ext_vector_type(8))) short bf16x8;
typedef __attribute__((ext_vector_type(4))) float f32x4;
typedef __attribute__((ext_vector_type(4))) short s16x4;

__device__ __forceinline__ short f2bf(float f) {
    union { float f; unsigned u; } a; a.f = f;
    unsigned r = a.u + 0x7FFFu + ((a.u >> 16) & 1u);   // RNE
    return (short)(r >> 16);
}

__device__ __forceinline__ void gload16(const short* g, short* l) {
    __builtin_amdgcn_global_load_lds(
        (const __attribute__((address_space(1))) unsigned int*)g,
        (__attribute__((address_space(3))) unsigned int*)l, 16, 0, 0);
}

__device__ __forceinline__ float sigmoidf_(float x) {
    return 1.0f / (1.0f + expf(-x));
}

// ---------------- f32 -> bf16 conversion (4 arrays in one launch) ----------------
__global__ void conv4_kernel(const float* __restrict__ s0, const float* __restrict__ s1,
                             const float* __restrict__ s2, const float* __restrict__ s3,
                             short* __restrict__ d0, short* __restrict__ d1,
                             short* __restrict__ d2, short* __restrict__ d3,
                             int* __restrict__ flags)
{
    const float* src; short* dst;
    if      (blockIdx.y == 0) { src = s0; dst = d0; }
    else if (blockIdx.y == 1) { src = s1; dst = d1; }
    else if (blockIdx.y == 2) { src = s2; dst = d2; }
    else                      { src = s3; dst = d3; }
    int i = blockIdx.x * blockDim.x + threadIdx.x;   // over NN*NN/4
    float4 v = reinterpret_cast<const float4*>(src)[i];
    s16x4 o;
    o.x = f2bf(v.x); o.y = f2bf(v.y); o.z = f2bf(v.z); o.w = f2bf(v.w);
    reinterpret_cast<s16x4*>(dst)[i] = o;
    if (blockIdx.y == 0 && blockIdx.x < NN / 256)
        flags[blockIdx.x * blockDim.x + threadIdx.x] = 0;
}

// ---------------- fused GEMM (C = A @ B^T, A:[M,K] bf16, B:[N,K] bf16) ----------------
// 128x128 tile, 8 waves (2x4), BK=64, double-buffered LDS, XOR-swizzled layout.
// EPI 1: v = 0.5*mp + sigmoid(acc+b1); spike detect/reset; v_bf16, n/m/h outs, flags
// EPI 2: bf16 sigmoid(acc+b2)
// EPI 3: f32  sigmoid(acc+b3)
template <int EPI>
__global__ __launch_bounds__(512) void gemm_fused(
    const short* __restrict__ A, const short* __restrict__ B,
    const float* __restrict__ bias,
    const float* __restrict__ mp,
    const float* __restrict__ n_in, const float* __restrict__ m_in,
    const float* __restrict__ h_in,
    short* __restrict__ out_bf, float* __restrict__ out_f,
    float* __restrict__ out_n, float* __restrict__ out_m,
    float* __restrict__ out_h,
    int* __restrict__ flags)
{
    __shared__ short As[2][128 * BK] __attribute__((aligned(16)));
    __shared__ short Bs[2][128 * BK] __attribute__((aligned(16)));

    const int tid  = threadIdx.x;
    const int lane = tid & 63;
    const int wid  = tid >> 6;          // 0..7
    const int row0 = blockIdx.y * 128;
    const int col0 = blockIdx.x * 128;
    const int wm   = (wid >> 2) * 64;   // wave sub-tile origin in M (0/64)
    const int wn   = (wid & 3) * 32;    // in N (0/32/64/96)
    const int lrow = lane & 15;
    const int lk16 = (lane >> 4) << 3;  // 0/8/16/24

    f32x4 acc[4][2] = {};

    // Stage one K-64 tile pair into the buffer given by COMPILE-TIME-derived
    // pointers. LDS dest linear (global_load_lds requirement); global source
    // inverse-swizzled so a swizzled ds_read returns linear fragments.
    auto stage = [&](short* asDst, short* bsDst, int k0) {
#pragma unroll
        for (int s = 0; s < 2; ++s) {
            int c = tid + s * 512;                       // chunk id 0..1023
            int r = c >> 3;                              // row in tile
            int ksrc = ((c & 7) ^ (r & 7)) << 3;         // swizzled k (bf16 elems)
            gload16(A + (size_t)(row0 + r) * NN + k0 + ksrc, asDst + c * 8);
            gload16(B + (size_t)(col0 + r) * NN + k0 + ksrc, bsDst + c * 8);
        }
    };

    auto compute = [&](const short* asSrc, const short* bsSrc) {
        bf16x8 af[4][2], bfv[2][2];
#pragma unroll
        for (int i = 0; i < 4; ++i) {
            const int row = wm + i * 16 + lrow;
#pragma unroll
            for (int kk = 0; kk < 2; ++kk) {
                const int ke = (lk16 + kk * 32) ^ ((row & 7) << 3);
                af[i][kk] = *reinterpret_cast<const bf16x8*>(&asSrc[row * BK + ke]);
            }
        }
#pragma unroll
        for (int j = 0; j < 2; ++j) {
            const int row = wn + j * 16 + lrow;
#pragma unroll
            for (int kk = 0; kk < 2; ++kk) {
                const int ke = (lk16 + kk * 32) ^ ((row & 7) << 3);
                bfv[j][kk] = *reinterpret_cast<const bf16x8*>(&bsSrc[row * BK + ke]);
            }
        }
#pragma unroll
        for (int kk = 0; kk < 2; ++kk)
#pragma unroll
            for (int i = 0; i < 4; ++i)
#pragma unroll
                for (int j = 0; j < 2; ++j)
                    acc[i][j] = __builtin_amdgcn_mfma_f32_16x16x32_bf16(
                        af[i][kk], bfv[j][kk], acc[i][j], 0, 0, 0);
    };

    short* As0 = &As[0][0]; short* As1 = &As[1][0];
    short* Bs0 = &Bs[0][0]; short* Bs1 = &Bs[1][0];

    // 2-phase pipeline, unrolled x2 so buffer identity is compile-time:
    // stage(next) issues before compute(cur); single vmcnt(0)+barrier per
    // phase (emitted by __syncthreads()), a full compute-phase after issue.
    stage(As0, Bs0, 0);
    __syncthreads();
#pragma unroll 1
    for (int t = 0; t < KT - 2; t += 2) {
        stage(As1, Bs1, (t + 1) * BK);
        compute(As0, Bs0);
        __syncthreads();
        stage(As0, Bs0, (t + 2) * BK);
        compute(As1, Bs1);
        __syncthreads();
    }
    stage(As1, Bs1, (KT - 1) * BK);
    compute(As0, Bs0);
    __syncthreads();
    compute(As1, Bs1);

    // epilogue — C/D layout: col = lane&15, row = (lane>>4)*4 + reg
#pragma unroll
    for (int i = 0; i < 4; ++i) {
#pragma unroll
        for (int j = 0; j < 2; ++j) {
            const int gcol = col0 + wn + j * 16 + lrow;
#pragma unroll
            for (int r = 0; r < 4; ++r) {
                const int grow = row0 + wm + i * 16 + ((lane >> 4) << 2) + r;
                const size_t idx = (size_t)grow * NN + gcol;
                float pre = acc[i][j][r] + bias[gcol];
                float sg  = sigmoidf_(pre);
                if constexpr (EPI == 1) {
                    float v = 0.5f * mp[gcol] + sg;
                    if (v > 1.0f) { flags[grow] = 1; v = 0.0f; }
                    out_bf[idx] = f2bf(v);
                    float an = 0.01f * (v + 55.0f) / (1.0f - expf(-(v + 55.0f) / 10.0f));
                    float bn = 0.125f * expf(-(v + 65.0f) / 80.0f);
                    float am = 0.1f  * (v + 40.0f) / (1.0f - expf(-(v + 40.0f) / 10.0f));
                    float bm = 4.0f  * expf(-(v + 65.0f) / 18.0f);
                    float ah = 0.07f * expf(-(v + 65.0f) / 20.0f);
                    float bh = 1.0f  / (1.0f + expf(-(v + 35.0f) / 10.0f));
                    float nv = n_in[gcol], mv = m_in[gcol], hv = h_in[gcol];
                    out_n[idx] = nv + 0.01f * (an * (1.0f - nv) - bn * nv);
                    out_m[idx] = mv + 0.01f * (am * (1.0f - mv) - bm * mv);
                    out_h[idx] = hv + 0.01f * (ah * (1.0f - hv) - bh * hv);
                } else if constexpr (EPI == 2) {
                    out_bf[idx] = f2bf(sg);
                } else {
                    out_f[idx] = sg;
                }
            }
        }
    }
}

// ---------------- STDP weight update ----------------
__global__ void stdp_kernel(const float* __restrict__ w, const float* __restrict__ lst,
                            const int* __restrict__ flags, float* __restrict__ outw)
{
    int idx = blockIdx.x * blockDim.x + threadIdx.x;  // over NN*NN/4
    int i  = idx >> 9;            // row  (NN/4 = 512 float4 per row)
    int j4 = (idx & 511) << 2;    // first col of the group
    float4 wv = reinterpret_cast<const float4*>(w)[idx];
    float o[4] = {wv.x, wv.y, wv.z, wv.w};
    const int   rsi = flags[i];
    const float tsi = 10.0f - lst[i];
#pragma unroll
    for (int t = 0; t < 4; ++t) {
        int j = j4 + t;
        if (rsi | flags[j]) {
            float dtm = tsi - (10.0f - lst[j]);
            float dw = (dtm > 0.0f) ? (-0.015f * expf(-fabsf(dtm) / 25.0f))
                                    : ( 0.02f  * expf(-fabsf(dtm) / 15.0f));
            o[t] += dw;
        }
        o[t] = fminf(1.0f, fmaxf(-1.0f, o[t]));
    }
    float4 ov = make_float4(o[0], o[1], o[2], o[3]);
    reinterpret_cast<float4*>(outw)[idx] = ov;
}

extern "C" void kernel_launch(void* const* d_in, const int* in_sizes, int n_in,
                              void* d_out, int out_size, void* d_ws, size_t ws_size,
                              hipStream_t stream)
{
    const float* x   = (const float*)d_in[0];
    const float* W1  = (const float*)d_in[1];
    const float* b1  = (const float*)d_in[2];
    const float* W2  = (const float*)d_in[3];
    const float* b2  = (const float*)d_in[4];
    const float* W3  = (const float*)d_in[5];
    const float* b3  = (const float*)d_in[6];
    const float* wts = (const float*)d_in[7];
    const float* lst = (const float*)d_in[8];
    const float* mp  = (const float*)d_in[9];
    const float* nin = (const float*)d_in[10];
    const float* min_ = (const float*)d_in[11];
    const float* hin = (const float*)d_in[12];

    const size_t NSQ = (size_t)NN * NN;
    float* out    = (float*)d_out;          // [N,N] final MLP output
    float* out_w  = out + NSQ;              // new_weights
    float* out_n  = out + 2 * NSQ;
    float* out_m  = out + 3 * NSQ;
    float* out_h  = out + 4 * NSQ;

    short* xb  = (short*)d_ws;
    short* w1b = xb  + NSQ;
    short* w2b = w1b + NSQ;
    short* w3b = w2b + NSQ;
    short* vb  = w3b + NSQ;
    short* h1b = vb  + NSQ;
    int*   flags = (int*)(h1b + NSQ);

    const int convBlocks = (int)(NSQ / 4 / 256);   // 4096 per array

    conv4_kernel<<<dim3(convBlocks, 4), 256, 0, stream>>>(x, W1, W2, W3,
                                                          xb, w1b, w2b, w3b, flags);

    dim3 grid(NT, NT);
    // GEMM1: v/HH/spike epilogue
    gemm_fused<1><<<grid, 512, 0, stream>>>(xb, w1b, b1, mp, nin, min_, hin,
                                            vb, nullptr, out_n, out_m, out_h, flags);
    // STDP weights (needs row flags from GEMM1)
    stdp_kernel<<<convBlocks, 256, 0, stream>>>(wts, lst, flags, out_w);
    // GEMM2: h1 = sigmoid(v@W2^T+b2) -> bf16
    gemm_fused<2><<<grid, 512, 0, stream>>>(vb, w2b, b2, nullptr, nullptr, nullptr, nullptr,
                                            h1b, nullptr, nullptr, nullptr, nullptr, nullptr);
    // GEMM3: out = sigmoid(h1@W3^T+b3) -> f32
    gemm_fused<3><<<grid, 512, 0, stream>>>(h1b, w3b, b3, nullptr, nullptr, nullptr, nullptr,
                                            nullptr, out, nullptr, nullptr, nullptr, nullptr);
}

// Round 7
// 133.896 us; speedup vs baseline: 1.2559x; 1.2559x over previous
//
#include <hip/hip_runtime.h>
#include <hip/hip_bf16.h>
#include <math.h>

// SpikingNeuralNetwork: 3 chained bf16-MFMA GEMMs + elementwise epilogues.
// N = 2048. Round 7: split-K=2 on the round-2 GEMM structure. 512 blocks =
// 2 co-resident blocks/CU (two independent barrier groups overlap; total
// staged bytes unchanged vs round 2). Partials in bf16; separate combine
// kernels apply the old fused epilogues.

#define NN 2048
#define BK 64
#define KHALF (NN / 2)
#define KTH (KHALF / BK)   // 16 K-tiles per half
#define NT (NN / 128)      // 16 tiles per dim

typedef __attribute__((ext_vector_type(8))) short bf16x8;
typedef __attribute__((ext_vector_type(4))) float f32x4;
typedef __attribute__((ext_vector_type(4))) short s16x4;

__device__ __forceinline__ short f2bf(float f) {
    union { float f; unsigned u; } a; a.f = f;
    unsigned r = a.u + 0x7FFFu + ((a.u >> 16) & 1u);   // RNE
    return (short)(r >> 16);
}

__device__ __forceinline__ float bf2f(short s) {
    union { unsigned u; float f; } a;
    a.u = ((unsigned)(unsigned short)s) << 16;
    return a.f;
}

__device__ __forceinline__ void gload16(const short* g, short* l) {
    __builtin_amdgcn_global_load_lds(
        (const __attribute__((address_space(1))) unsigned int*)g,
        (__attribute__((address_space(3))) unsigned int*)l, 16, 0, 0);
}

__device__ __forceinline__ float sigmoidf_(float x) {
    return 1.0f / (1.0f + expf(-x));
}

// ---------------- f32 -> bf16 conversions ----------------
__global__ void conv3_kernel(const float* __restrict__ s0, const float* __restrict__ s1,
                             const float* __restrict__ s2,
                             short* __restrict__ d0, short* __restrict__ d1,
                             short* __restrict__ d2, int* __restrict__ flags)
{
    const float* src; short* dst;
    if      (blockIdx.y == 0) { src = s0; dst = d0; }
    else if (blockIdx.y == 1) { src = s1; dst = d1; }
    else                      { src = s2; dst = d2; }
    int i = blockIdx.x * blockDim.x + threadIdx.x;   // over NN*NN/4
    float4 v = reinterpret_cast<const float4*>(src)[i];
    s16x4 o;
    o.x = f2bf(v.x); o.y = f2bf(v.y); o.z = f2bf(v.z); o.w = f2bf(v.w);
    reinterpret_cast<s16x4*>(dst)[i] = o;
    if (blockIdx.y == 0 && blockIdx.x < NN / 256)
        flags[blockIdx.x * blockDim.x + threadIdx.x] = 0;
}

__global__ void conv1_kernel(const float* __restrict__ src, short* __restrict__ dst) {
    int i = blockIdx.x * blockDim.x + threadIdx.x;
    float4 v = reinterpret_cast<const float4*>(src)[i];
    s16x4 o;
    o.x = f2bf(v.x); o.y = f2bf(v.y); o.z = f2bf(v.z); o.w = f2bf(v.w);
    reinterpret_cast<s16x4*>(dst)[i] = o;
}

// ---------------- split-K GEMM partial (C_kb = A[:,kb*1024+...] @ B^T slice) ----------
// 128x128 tile, 8 waves (2x4), BK=64, double-buffered LDS, XOR-swizzled layout.
// blockIdx.z = kb selects the K-half; partial written as bf16 to P + kb*NSQ.
__global__ __launch_bounds__(512) void gemm_partial(
    const short* __restrict__ A, const short* __restrict__ B,
    short* __restrict__ P)
{
    __shared__ short As[2][128 * BK] __attribute__((aligned(16)));
    __shared__ short Bs[2][128 * BK] __attribute__((aligned(16)));

    const int tid  = threadIdx.x;
    const int lane = tid & 63;
    const int wid  = tid >> 6;          // 0..7
    const int row0 = blockIdx.y * 128;
    const int col0 = blockIdx.x * 128;
    const int kbase = blockIdx.z * KHALF;
    const int wm   = (wid >> 2) * 64;   // wave sub-tile origin in M (0/64)
    const int wn   = (wid & 3) * 32;    // in N (0/32/64/96)
    const int lrow = lane & 15;
    const int lk16 = (lane >> 4) << 3;  // 0/8/16/24

    f32x4 acc[4][2] = {};

    // LDS dest linear (global_load_lds requirement); global source inverse-
    // swizzled so a swizzled ds_read returns linear fragments (rule #21).
    auto stage = [&](int buf, int k0) {
#pragma unroll
        for (int s = 0; s < 2; ++s) {
            int c = tid + s * 512;                       // chunk id 0..1023
            int r = c >> 3;                              // row in tile
            int ksrc = ((c & 7) ^ (r & 7)) << 3;         // swizzled k (bf16 elems)
            gload16(A + (size_t)(row0 + r) * NN + k0 + ksrc, &As[buf][c * 8]);
            gload16(B + (size_t)(col0 + r) * NN + k0 + ksrc, &Bs[buf][c * 8]);
        }
    };

    auto compute = [&](int buf) {
        bf16x8 af[4][2], bfv[2][2];
#pragma unroll
        for (int i = 0; i < 4; ++i) {
            const int row = wm + i * 16 + lrow;
#pragma unroll
            for (int kk = 0; kk < 2; ++kk) {
                const int ke = (lk16 + kk * 32) ^ ((row & 7) << 3);
                af[i][kk] = *reinterpret_cast<const bf16x8*>(&As[buf][row * BK + ke]);
            }
        }
#pragma unroll
        for (int j = 0; j < 2; ++j) {
            const int row = wn + j * 16 + lrow;
#pragma unroll
            for (int kk = 0; kk < 2; ++kk) {
                const int ke = (lk16 + kk * 32) ^ ((row & 7) << 3);
                bfv[j][kk] = *reinterpret_cast<const bf16x8*>(&Bs[buf][row * BK + ke]);
            }
        }
#pragma unroll
        for (int kk = 0; kk < 2; ++kk)
#pragma unroll
            for (int i = 0; i < 4; ++i)
#pragma unroll
                for (int j = 0; j < 2; ++j)
                    acc[i][j] = __builtin_amdgcn_mfma_f32_16x16x32_bf16(
                        af[i][kk], bfv[j][kk], acc[i][j], 0, 0, 0);
    };

    // 2-phase pipeline: STAGE(next) before compute(cur); one vmcnt(0)+barrier
    // per iteration (__syncthreads). With 2 blocks/CU the other block's
    // compute fills this block's drain stall.
    stage(0, kbase);
    __syncthreads();
    int cur = 0;
    for (int t = 0; t < KTH - 1; ++t) {
        stage(cur ^ 1, kbase + (t + 1) * BK);
        compute(cur);
        __syncthreads();
        cur ^= 1;
    }
    compute(cur);

    // write bf16 partial — C/D layout: col = lane&15, row = (lane>>4)*4 + reg
    short* outp = P + (size_t)blockIdx.z * NN * NN;
#pragma unroll
    for (int i = 0; i < 4; ++i) {
#pragma unroll
        for (int j = 0; j < 2; ++j) {
            const int gcol = col0 + wn + j * 16 + lrow;
#pragma unroll
            for (int r = 0; r < 4; ++r) {
                const int grow = row0 + wm + i * 16 + ((lane >> 4) << 2) + r;
                outp[(size_t)grow * NN + gcol] = f2bf(acc[i][j][r]);
            }
        }
    }
}

// ---------------- combine partials + epilogue ----------------
// EPI 1: v = 0.5*mp + sigmoid(p0+p1+b1); spike; v->bf16, n/m/h outs, flags
// EPI 2: bf16 sigmoid(p0+p1+b2)
// EPI 3: f32  sigmoid(p0+p1+b3)
template <int EPI>
__global__ void combine_kernel(
    const short* __restrict__ p0, const short* __restrict__ p1,
    const float* __restrict__ bias,
    const float* __restrict__ mp,
    const float* __restrict__ n_in, const float* __restrict__ m_in,
    const float* __restrict__ h_in,
    short* __restrict__ out_bf, float* __restrict__ out_f,
    float* __restrict__ out_n, float* __restrict__ out_m,
    float* __restrict__ out_h,
    int* __restrict__ flags)
{
    int idx = blockIdx.x * blockDim.x + threadIdx.x;   // over NN*NN/4
    int row = idx >> 9;            // NN/4 = 512 groups per row
    int g   = idx & 511;           // float4 group within row
    s16x4 a = reinterpret_cast<const s16x4*>(p0)[idx];
    s16x4 b = reinterpret_cast<const s16x4*>(p1)[idx];
    float4 bi = reinterpret_cast<const float4*>(bias)[g];
    float pre[4] = { bf2f(a.x) + bf2f(b.x) + bi.x,
                     bf2f(a.y) + bf2f(b.y) + bi.y,
                     bf2f(a.z) + bf2f(b.z) + bi.z,
                     bf2f(a.w) + bf2f(b.w) + bi.w };
    if constexpr (EPI == 1) {
        float4 mp4 = reinterpret_cast<const float4*>(mp)[g];
        float4 n4  = reinterpret_cast<const float4*>(n_in)[g];
        float4 m4  = reinterpret_cast<const float4*>(m_in)[g];
        float4 h4  = reinterpret_cast<const float4*>(h_in)[g];
        float mpv[4] = {mp4.x, mp4.y, mp4.z, mp4.w};
        float nv[4]  = {n4.x, n4.y, n4.z, n4.w};
        float mv[4]  = {m4.x, m4.y, m4.z, m4.w};
        float hv[4]  = {h4.x, h4.y, h4.z, h4.w};
        s16x4 vb;
        float on[4], om[4], oh[4];
#pragma unroll
        for (int t = 0; t < 4; ++t) {
            float v = 0.5f * mpv[t] + sigmoidf_(pre[t]);
            if (v > 1.0f) { flags[row] = 1; v = 0.0f; }
            vb[t] = f2bf(v);
            float an = 0.01f * (v + 55.0f) / (1.0f - expf(-(v + 55.0f) / 10.0f));
            float bn = 0.125f * expf(-(v + 65.0f) / 80.0f);
            float am = 0.1f  * (v + 40.0f) / (1.0f - expf(-(v + 40.0f) / 10.0f));
            float bm = 4.0f  * expf(-(v + 65.0f) / 18.0f);
            float ah = 0.07f * expf(-(v + 65.0f) / 20.0f);
            float bh = 1.0f  / (1.0f + expf(-(v + 35.0f) / 10.0f));
            on[t] = nv[t] + 0.01f * (an * (1.0f - nv[t]) - bn * nv[t]);
            om[t] = mv[t] + 0.01f * (am * (1.0f - mv[t]) - bm * mv[t]);
            oh[t] = hv[t] + 0.01f * (ah * (1.0f - hv[t]) - bh * hv[t]);
        }
        reinterpret_cast<s16x4*>(out_bf)[idx] = vb;
        reinterpret_cast<float4*>(out_n)[idx] = make_float4(on[0], on[1], on[2], on[3]);
        reinterpret_cast<float4*>(out_m)[idx] = make_float4(om[0], om[1], om[2], om[3]);
        reinterpret_cast<float4*>(out_h)[idx] = make_float4(oh[0], oh[1], oh[2], oh[3]);
    } else if constexpr (EPI == 2) {
        s16x4 o;
        o.x = f2bf(sigmoidf_(pre[0])); o.y = f2bf(sigmoidf_(pre[1]));
        o.z = f2bf(sigmoidf_(pre[2])); o.w = f2bf(sigmoidf_(pre[3]));
        reinterpret_cast<s16x4*>(out_bf)[idx] = o;
    } else {
        reinterpret_cast<float4*>(out_f)[idx] =
            make_float4(sigmoidf_(pre[0]), sigmoidf_(pre[1]),
                        sigmoidf_(pre[2]), sigmoidf_(pre[3]));
    }
}

// ---------------- STDP weight update ----------------
__global__ void stdp_kernel(const float* __restrict__ w, const float* __restrict__ lst,
                            const int* __restrict__ flags, float* __restrict__ outw)
{
    int idx = blockIdx.x * blockDim.x + threadIdx.x;  // over NN*NN/4
    int i  = idx >> 9;            // row  (NN/4 = 512 float4 per row)
    int j4 = (idx & 511) << 2;    // first col of the group
    float4 wv = reinterpret_cast<const float4*>(w)[idx];
    float o[4] = {wv.x, wv.y, wv.z, wv.w};
    const int   rsi = flags[i];
    const float tsi = 10.0f - lst[i];
#pragma unroll
    for (int t = 0; t < 4; ++t) {
        int j = j4 + t;
        if (rsi | flags[j]) {
            float dtm = tsi - (10.0f - lst[j]);
            float dw = (dtm > 0.0f) ? (-0.015f * expf(-fabsf(dtm) / 25.0f))
                                    : ( 0.02f  * expf(-fabsf(dtm) / 15.0f));
            o[t] += dw;
        }
        o[t] = fminf(1.0f, fmaxf(-1.0f, o[t]));
    }
    float4 ov = make_float4(o[0], o[1], o[2], o[3]);
    reinterpret_cast<float4*>(outw)[idx] = ov;
}

extern "C" void kernel_launch(void* const* d_in, const int* in_sizes, int n_in,
                              void* d_out, int out_size, void* d_ws, size_t ws_size,
                              hipStream_t stream)
{
    const float* x   = (const float*)d_in[0];
    const float* W1  = (const float*)d_in[1];
    const float* b1  = (const float*)d_in[2];
    const float* W2  = (const float*)d_in[3];
    const float* b2  = (const float*)d_in[4];
    const float* W3  = (const float*)d_in[5];
    const float* b3  = (const float*)d_in[6];
    const float* wts = (const float*)d_in[7];
    const float* lst = (const float*)d_in[8];
    const float* mp  = (const float*)d_in[9];
    const float* nin = (const float*)d_in[10];
    const float* min_ = (const float*)d_in[11];
    const float* hin = (const float*)d_in[12];

    const size_t NSQ = (size_t)NN * NN;
    float* out    = (float*)d_out;          // [N,N] final MLP output
    float* out_w  = out + NSQ;              // new_weights
    float* out_n  = out + 2 * NSQ;
    float* out_m  = out + 3 * NSQ;
    float* out_h  = out + 4 * NSQ;

    // ws layout (48 MB + flags): R1,R2,R3,R4 bf16 8MB each; P = 2x8MB bf16 partials
    short* R1 = (short*)d_ws;       // xb, later w3b
    short* R2 = R1 + NSQ;           // w1b, later h1b
    short* R3 = R2 + NSQ;           // vb
    short* R4 = R3 + NSQ;           // w2b
    short* P  = R4 + NSQ;           // partials [2][NSQ]
    int* flags = (int*)(P + 2 * NSQ);

    const int convBlocks = (int)(NSQ / 4 / 256);   // 4096 per array

    // x->R1, W1->R2, W2->R4 (+ zero flags)
    conv3_kernel<<<dim3(convBlocks, 3), 256, 0, stream>>>(x, W1, W2, R1, R2, R4, flags);

    dim3 grid(NT, NT, 2);   // 512 blocks, blockIdx.z = K-half
    // GEMM1 partials: x @ W1^T
    gemm_partial<<<grid, 512, 0, stream>>>(R1, R2, P);
    // W3 -> R1 (x is dead after GEMM1 partials)
    conv1_kernel<<<convBlocks, 256, 0, stream>>>(W3, R1);
    // combine1: v/HH/spike epilogue -> vb(R3), out_n/m/h, flags
    combine_kernel<1><<<convBlocks, 256, 0, stream>>>(P, P + NSQ, b1, mp, nin, min_, hin,
                                                      R3, nullptr, out_n, out_m, out_h, flags);
    // STDP weights (needs row flags from combine1)
    stdp_kernel<<<convBlocks, 256, 0, stream>>>(wts, lst, flags, out_w);
    // GEMM2 partials: v @ W2^T
    gemm_partial<<<grid, 512, 0, stream>>>(R3, R4, P);
    // combine2: h1 = sigmoid(.) -> bf16 (R2; w1b dead)
    combine_kernel<2><<<convBlocks, 256, 0, stream>>>(P, P + NSQ, b2, nullptr, nullptr, nullptr,
                                                      nullptr, R2, nullptr, nullptr, nullptr,
                                                      nullptr, nullptr);
    // GEMM3 partials: h1 @ W3^T
    gemm_partial<<<grid, 512, 0, stream>>>(R2, R1, P);
    // combine3: out = sigmoid(.) -> f32
    combine_kernel<3><<<convBlocks, 256, 0, stream>>>(P, P + NSQ, b3, nullptr, nullptr, nullptr,
                                                      nullptr, nullptr, out, nullptr, nullptr,
                                                      nullptr, nullptr);
}